// Round 2
// baseline (26034.528 us; speedup 1.0000x reference)
//
#include <hip/hip_runtime.h>
#include <stdint.h>

#define NV 32000
#define NE 256
#define NH 512
#define NB 32
#define NS 256
#define NT 64
#define NG 1536   // 3*NH

typedef unsigned short u16;
typedef unsigned int   u32;
typedef short bf16x8 __attribute__((ext_vector_type(8)));
typedef float f32x4  __attribute__((ext_vector_type(4)));

__device__ __forceinline__ u16 f2bf(float x){
  u32 u = __float_as_uint(x);
  u32 r = (u + 0x7FFFu + ((u >> 16) & 1u)) >> 16;   // RNE
  return (u16)r;
}
__device__ __forceinline__ float bf2f(u16 b){ return __uint_as_float(((u32)b) << 16); }
__device__ __forceinline__ float sigm(float x){ return 1.0f / (1.0f + expf(-x)); }

// ---------------- grid barrier (sense-reversing, device scope) ----------------
// Release fence BEFORE arrive (so all threads' stores are device-visible when the
// signal lands), acquire fence AFTER the wait.
__device__ __forceinline__ void grid_bar(int* bar, int nb){
  __threadfence();            // release: L2 writeback so other XCDs see our stores
  __syncthreads();            // all threads' fences retired before tid0 signals
  if (threadIdx.x == 0){
    int* ctr = bar;
    int* gen = bar + 256;     // separate cacheline
    int g = __hip_atomic_load(gen, __ATOMIC_RELAXED, __HIP_MEMORY_SCOPE_AGENT);
    int a = __hip_atomic_fetch_add(ctr, 1, __ATOMIC_ACQ_REL, __HIP_MEMORY_SCOPE_AGENT);
    if (a == nb - 1){
      __hip_atomic_store(ctr, 0, __ATOMIC_RELAXED, __HIP_MEMORY_SCOPE_AGENT);
      __hip_atomic_fetch_add(gen, 1, __ATOMIC_RELEASE, __HIP_MEMORY_SCOPE_AGENT);
    } else {
      while (__hip_atomic_load(gen, __ATOMIC_ACQUIRE, __HIP_MEMORY_SCOPE_AGENT) == g)
        __builtin_amdgcn_s_sleep(2);
    }
  }
  __syncthreads();
  __threadfence();            // acquire: invalidate L1/L2 so we see others' stores
}

// ---------------- init: zero h0 and barrier state ----------------
__global__ void init_k(float* __restrict__ hbuf, int* __restrict__ bar){
  int i = blockIdx.x * 256 + threadIdx.x;
  if (i < NB*NH) hbuf[i] = 0.0f;
  if (blockIdx.x == 0 && threadIdx.x < 512) bar[threadIdx.x] = 0;
}

// ---------------- embedding gather (f32 rows) ----------------
__global__ void gather_k(const float* __restrict__ table, const int* __restrict__ idx,
                         float* __restrict__ outp){
  int r = blockIdx.x, c = threadIdx.x;            // 64 threads * 4 f32 = 256 cols
  int row = idx[r];
  float4 v = ((const float4*)(table + (size_t)row * NE))[c];
  ((float4*)(outp + (size_t)r*NE))[c] = v;
}

// ---------------- GEMM: C[M,N] = A * B^T + bias, A f32 split hi/lo in-stage ----
// A: f32 [M,K] row-major. B: f32 [N,K] row-major (single bf16 in-stage).
// Tiles 128x128x32, 256 threads (4 waves, 2x2 wave grid, 64x64 each).
__device__ __forceinline__ void st_hilo8(u16* ph, u16* pl, float4 va, float4 vb){
  float f[8] = {va.x,va.y,va.z,va.w,vb.x,vb.y,vb.z,vb.w};
  u32 hw[4], lw[4];
  #pragma unroll
  for (int i=0;i<4;i++){
    u16 h0 = f2bf(f[2*i]),               h1 = f2bf(f[2*i+1]);
    u16 l0 = f2bf(f[2*i]   - bf2f(h0));
    u16 l1 = f2bf(f[2*i+1] - bf2f(h1));
    hw[i] = (u32)h0 | ((u32)h1 << 16);
    lw[i] = (u32)l0 | ((u32)l1 << 16);
  }
  *(uint4*)ph = *(const uint4*)hw;
  *(uint4*)pl = *(const uint4*)lw;
}
__device__ __forceinline__ void st_b8(u16* p, float4 va, float4 vb){
  u32 w[4];
  w[0] = (u32)f2bf(va.x) | ((u32)f2bf(va.y) << 16);
  w[1] = (u32)f2bf(va.z) | ((u32)f2bf(va.w) << 16);
  w[2] = (u32)f2bf(vb.x) | ((u32)f2bf(vb.y) << 16);
  w[3] = (u32)f2bf(vb.z) | ((u32)f2bf(vb.w) << 16);
  *(uint4*)p = *(const uint4*)w;
}

__global__ __launch_bounds__(256, 2)
void gemm_k(const float* __restrict__ Am, int lda,
            const float* __restrict__ Bm, int ldb, const float* __restrict__ bias,
            float* __restrict__ C, int ldc, int K, int mswap)
{
  __shared__ u16 sAh[128][40];
  __shared__ u16 sAl[128][40];
  __shared__ u16 sB [128][40];
  const int tid = threadIdx.x;
  const int bm = mswap ? blockIdx.x : blockIdx.y;
  const int bn = mswap ? blockIdx.y : blockIdx.x;
  const int m0 = bm * 128, n0 = bn * 128;
  const int w = tid >> 6, lane = tid & 63;
  const int wr = w >> 1, wc = w & 1;
  const int fr = lane & 15, fq = lane >> 4;
  const int fk = fq * 8;

  f32x4 acc[4][4];
  #pragma unroll
  for (int i=0;i<4;i++)
    #pragma unroll
    for (int j=0;j<4;j++)
      #pragma unroll
      for (int e=0;e<4;e++) acc[i][j][e] = 0.0f;

  const int srow = tid >> 1;
  const int sh16 = (tid & 1) * 16;
  const float* gA = Am + (size_t)(m0 + srow)*lda + sh16;
  const float* gB = Bm + (size_t)(n0 + srow)*ldb + sh16;

  float4 ra0 = *(const float4*)(gA),      ra1 = *(const float4*)(gA + 4);
  float4 ra2 = *(const float4*)(gA + 8),  ra3 = *(const float4*)(gA + 12);
  float4 rb0 = *(const float4*)(gB),      rb1 = *(const float4*)(gB + 4);
  float4 rb2 = *(const float4*)(gB + 8),  rb3 = *(const float4*)(gB + 12);

  for (int k0 = 0; k0 < K; k0 += 32){
    st_hilo8(&sAh[srow][sh16],   &sAl[srow][sh16],   ra0, ra1);
    st_hilo8(&sAh[srow][sh16+8], &sAl[srow][sh16+8], ra2, ra3);
    st_b8(&sB[srow][sh16],   rb0, rb1);
    st_b8(&sB[srow][sh16+8], rb2, rb3);

    if (k0 + 32 < K){   // prefetch next K-tile
      ra0 = *(const float4*)(gA + k0+32); ra1 = *(const float4*)(gA + k0+36);
      ra2 = *(const float4*)(gA + k0+40); ra3 = *(const float4*)(gA + k0+44);
      rb0 = *(const float4*)(gB + k0+32); rb1 = *(const float4*)(gB + k0+36);
      rb2 = *(const float4*)(gB + k0+40); rb3 = *(const float4*)(gB + k0+44);
    }
    __syncthreads();
    bf16x8 afh[4], afl[4], bfv[4];
    #pragma unroll
    for (int i=0;i<4;i++){
      afh[i] = *(const bf16x8*)&sAh[wr*64 + i*16 + fr][fk];
      afl[i] = *(const bf16x8*)&sAl[wr*64 + i*16 + fr][fk];
    }
    #pragma unroll
    for (int jj=0;jj<4;jj++) bfv[jj] = *(const bf16x8*)&sB[wc*64 + jj*16 + fr][fk];
    #pragma unroll
    for (int i=0;i<4;i++)
      #pragma unroll
      for (int jj=0;jj<4;jj++){
        acc[i][jj] = __builtin_amdgcn_mfma_f32_16x16x32_bf16(afh[i], bfv[jj], acc[i][jj], 0,0,0);
        acc[i][jj] = __builtin_amdgcn_mfma_f32_16x16x32_bf16(afl[i], bfv[jj], acc[i][jj], 0,0,0);
      }
    __syncthreads();
  }
  #pragma unroll
  for (int jj=0;jj<4;jj++){
    int gn = n0 + wc*64 + jj*16 + fr;
    float bv = bias[gn];
    #pragma unroll
    for (int i=0;i<4;i++){
      int gm = m0 + wr*64 + i*16 + fq*4;
      #pragma unroll
      for (int e=0;e<4;e++)
        C[(size_t)(gm + e)*ldc + gn] = acc[i][jj][e] + bv;
    }
  }
}

// swizzle helper for LDS float4 layout (breaks 128B-stride bank conflicts)
__device__ __forceinline__ int swz(int c){ return c ^ ((c >> 3) & 7); }

// ---------------- encoder recurrence: persistent, 64 blocks x 1024 ----------------
// block owns 8 j-cols; thread (kg:16 k-slices of 32, jl:8, bq:8 -> 4 b's). Whh in regs.
__global__ __launch_bounds__(1024, 1)
void enc_rec_k(const float* __restrict__ gi, const float* __restrict__ Whh,
               const float* __restrict__ bhh, float* __restrict__ hbuf,
               float* __restrict__ enc_out, int* __restrict__ bar)
{
  __shared__ float hl[NB*NH];    // 64KB, float4-swizzled
  const int tid = threadIdx.x, bid = blockIdx.x;
  const int kg = tid & 15;
  const int jl = (tid >> 4) & 7;
  const int bq = tid >> 7;
  const int j  = bid * 8 + jl;
  float w0[32], w1[32], w2[32];
  {
    const float* p0 = Whh + (size_t)(0*NH + j)*NH + kg*32;
    const float* p1 = Whh + (size_t)(1*NH + j)*NH + kg*32;
    const float* p2 = Whh + (size_t)(2*NH + j)*NH + kg*32;
    #pragma unroll
    for (int q=0;q<8;q++){
      *(float4*)&w0[q*4] = *(const float4*)(p0 + q*4);
      *(float4*)&w1[q*4] = *(const float4*)(p1 + q*4);
      *(float4*)&w2[q*4] = *(const float4*)(p2 + q*4);
    }
  }
  const float b0 = bhh[j], b1 = bhh[NH+j], b2 = bhh[2*NH+j];
  int cur = 0;
  for (int s=0; s<NS; s++){
    const float* hsrc = hbuf + cur*(NB*NH);
    float g0[4], g1[4], g2[4], hold[4];
    if (kg == 0){                      // prefetch gate inputs early (overlap)
      #pragma unroll
      for (int u=0;u<4;u++){
        int b = bq*4 + u;
        const float* gp = gi + ((size_t)b*NS + s)*NG;
        g0[u] = gp[j]; g1[u] = gp[NH+j]; g2[u] = gp[2*NH+j];
        hold[u] = hsrc[b*NH + j];
      }
    }
    #pragma unroll
    for (int u=0;u<4;u++){             // stage h into swizzled LDS
      int i4 = tid + u*1024;
      int b = i4 >> 7, c = i4 & 127;
      ((float4*)hl)[b*128 + swz(c)] = ((const float4*)hsrc)[i4];
    }
    __syncthreads();
    float a0[4], a1[4], a2[4];
    #pragma unroll
    for (int u=0;u<4;u++){
      int b = bq*4 + u;
      float hv[32];
      #pragma unroll
      for (int q=0;q<8;q++)
        *(float4*)&hv[q*4] = ((float4*)hl)[b*128 + kg*8 + (q ^ (kg & 7))];
      float s0=0.f, s1=0.f, s2=0.f;
      #pragma unroll
      for (int kk=0;kk<32;kk++){ s0+=w0[kk]*hv[kk]; s1+=w1[kk]*hv[kk]; s2+=w2[kk]*hv[kk]; }
      a0[u]=s0; a1[u]=s1; a2[u]=s2;
    }
    #pragma unroll
    for (int m=1;m<16;m<<=1){
      #pragma unroll
      for (int u=0;u<4;u++){
        a0[u] += __shfl_xor(a0[u], m);
        a1[u] += __shfl_xor(a1[u], m);
        a2[u] += __shfl_xor(a2[u], m);
      }
    }
    if (kg == 0){
      #pragma unroll
      for (int u=0;u<4;u++){
        int b = bq*4 + u;
        float r = sigm(g0[u] + a0[u] + b0);
        float z = sigm(g1[u] + a1[u] + b1);
        float n = tanhf(g2[u] + r*(a2[u] + b2));
        float hn = (1.0f - z)*n + z*hold[u];
        hbuf[(cur^1)*(NB*NH) + b*NH + j] = hn;
        enc_out[((size_t)b*NS + s)*NH + j] = hn;
      }
    }
    cur ^= 1;
    grid_bar(bar, 64);
  }
}

// ---------------- decoder recurrence: persistent, 64 blocks x 1024, 3 phases/step ----
__global__ __launch_bounds__(1024, 1)
void dec_rec_k(const float* __restrict__ gi, const float* __restrict__ Whh,
               const float* __restrict__ Wih, const float* __restrict__ bhh,
               const float* __restrict__ enc_out, const int* __restrict__ src,
               float* __restrict__ hbuf, float* __restrict__ scores,
               float* __restrict__ ctx, float* __restrict__ pred,
               int* __restrict__ bar)
{
  __shared__ float pool[16384];   // 64KB
  const int tid = threadIdx.x, bid = blockIdx.x;
  const int lane = tid & 63, wv = tid >> 6;
  // phase C mapping: kg: 32 k-slices of 32 over k=1024 (h||ctx); rl: 8 j's; bq: 4
  const int kg = tid & 31;
  const int rl = (tid >> 5) & 7;
  const int bq = tid >> 8;
  const int jC = bid * 8 + rl;
  float w0[32], w1[32], w2[32];
  {
    const float* p0 = (kg < 16) ? (Whh + (size_t)(0*NH+jC)*NH + kg*32)
                                : (Wih + (size_t)(0*NH+jC)*768 + NE + (kg-16)*32);
    const float* p1 = (kg < 16) ? (Whh + (size_t)(1*NH+jC)*NH + kg*32)
                                : (Wih + (size_t)(1*NH+jC)*768 + NE + (kg-16)*32);
    const float* p2 = (kg < 16) ? (Whh + (size_t)(2*NH+jC)*NH + kg*32)
                                : (Wih + (size_t)(2*NH+jC)*768 + NE + (kg-16)*32);
    #pragma unroll
    for (int q=0;q<8;q++){
      *(float4*)&w0[q*4] = *(const float4*)(p0 + q*4);
      *(float4*)&w1[q*4] = *(const float4*)(p1 + q*4);
      *(float4*)&w2[q*4] = *(const float4*)(p2 + q*4);
    }
  }
  const float b0h = bhh[jC], b1h = bhh[NH+jC], b2h = bhh[2*NH+jC];
  const int bA = bid >> 1, shalf = bid & 1;   // phase A: 128 s each
  const int bB = bid >> 1, hh = bid & 1;      // phase B: 256 h-cols each

  int cur = 0;
  for (int t=0; t<NT; t++){
    // ---- A: scores = enc_out . h, masked ----
    {
      const float* hp = hbuf + cur*(NB*NH) + bA*NH + lane*8;
      float hr[8];
      *(float4*)&hr[0] = *(const float4*)(hp);
      *(float4*)&hr[4] = *(const float4*)(hp + 4);
      #pragma unroll
      for (int p=0;p<8;p++){
        int s = shalf*128 + wv*8 + p;
        const float* eo = enc_out + ((size_t)bA*NS + s)*NH + lane*8;
        float4 e0 = *(const float4*)eo;
        float4 e1 = *(const float4*)(eo + 4);
        float d = e0.x*hr[0] + e0.y*hr[1] + e0.z*hr[2] + e0.w*hr[3]
                + e1.x*hr[4] + e1.y*hr[5] + e1.z*hr[6] + e1.w*hr[7];
        #pragma unroll
        for (int m=1;m<64;m<<=1) d += __shfl_xor(d, m);
        if (lane == 0){
          int tok = src[bA*NS + s];
          scores[bA*NS + s] = (tok == 0) ? -1e9f : d;
        }
      }
    }
    grid_bar(bar, 64);
    // ---- B: softmax + context ----
    {
      float* attn = pool + 256;
      float* red  = pool + 512;
      float* part = pool + 1024;   // [4][256]
      float sv = 0.0f;
      if (tid < 256) sv = scores[bB*NS + tid];
      float mx = sv;
      #pragma unroll
      for (int m=1;m<64;m<<=1) mx = fmaxf(mx, __shfl_xor(mx, m));
      if (tid < 256 && lane == 0) red[wv] = mx;
      __syncthreads();
      mx = fmaxf(fmaxf(red[0], red[1]), fmaxf(red[2], red[3]));
      float ex = (tid < 256) ? expf(sv - mx) : 0.0f;
      float sm = ex;
      #pragma unroll
      for (int m=1;m<64;m<<=1) sm += __shfl_xor(sm, m);
      if (tid < 256 && lane == 0) red[8 + wv] = sm;
      __syncthreads();
      float tot = red[8] + red[9] + red[10] + red[11];
      if (tid < 256) attn[tid] = ex / tot;
      __syncthreads();
      int hk = hh*256 + (tid & 255), sq = tid >> 8;
      float a = 0.0f;
      for (int s5=0; s5<64; s5++){
        int s = sq*64 + s5;
        a += attn[s] * enc_out[((size_t)bB*NS + s)*NH + hk];
      }
      part[sq*256 + (tid & 255)] = a;
      __syncthreads();
      if (tid < 256){
        float c = part[tid] + part[256+tid] + part[512+tid] + part[768+tid];
        ctx[bB*NH + hh*256 + tid] = c;
        pred[((size_t)bB*NT + t)*1024 + NH + hh*256 + tid] = c;
      }
    }
    grid_bar(bar, 64);
    // ---- C: gh (h-part) + gi (ctx-part) + gates; 2 passes of 16 b (64KB LDS) ----
    {
      const float* hsrc = hbuf + cur*(NB*NH);
      #pragma unroll 1
      for (int p2=0; p2<2; ++p2){
        float* hc = pool;   // [16][256 float4] swizzled: h || ctx per row
        float gp0[4], gp1[4], gp2v[4], hold[4];
        if (kg == 0){
          #pragma unroll
          for (int u=0;u<4;u++){
            int b = p2*16 + bq*4 + u;
            const float* gp = gi + ((size_t)b*NT + t)*NG;
            gp0[u] = gp[jC]; gp1[u] = gp[NH+jC]; gp2v[u] = gp[2*NH+jC];
            hold[u] = hsrc[b*NH + jC];
          }
        }
        #pragma unroll
        for (int u=0;u<4;u++){
          int i4 = tid + u*1024;         // 4096 f4 = 16 b x 256
          int bl = i4 >> 8, c = i4 & 255;
          float4 v;
          if (c < 128) v = ((const float4*)hsrc)[(p2*16+bl)*128 + c];
          else         v = ((const float4*)ctx)[(p2*16+bl)*128 + (c - 128)];
          ((float4*)hc)[bl*256 + swz(c)] = v;
        }
        __syncthreads();
        float a0[4], a1[4], a2[4];
        #pragma unroll
        for (int u=0;u<4;u++){
          int bl = bq*4 + u;
          float hv[32];
          #pragma unroll
          for (int q=0;q<8;q++)
            *(float4*)&hv[q*4] = ((float4*)hc)[bl*256 + kg*8 + (q ^ (kg & 7))];
          float s0=0.f,s1=0.f,s2=0.f;
          #pragma unroll
          for (int kk=0;kk<32;kk++){ s0+=w0[kk]*hv[kk]; s1+=w1[kk]*hv[kk]; s2+=w2[kk]*hv[kk]; }
          a0[u]=s0; a1[u]=s1; a2[u]=s2;
        }
        #pragma unroll
        for (int m=1;m<16;m<<=1){
          #pragma unroll
          for (int u=0;u<4;u++){
            a0[u]+=__shfl_xor(a0[u],m); a1[u]+=__shfl_xor(a1[u],m); a2[u]+=__shfl_xor(a2[u],m);
          }
        }
        float o0[4], o1[4], o2[4];   // other half (gh at kg0 <-> gi-ctx at kg16)
        #pragma unroll
        for (int u=0;u<4;u++){
          o0[u]=__shfl_xor(a0[u],16); o1[u]=__shfl_xor(a1[u],16); o2[u]=__shfl_xor(a2[u],16);
        }
        if (kg == 0){
          #pragma unroll
          for (int u=0;u<4;u++){
            int b = p2*16 + bq*4 + u;
            float r = sigm(gp0[u] + o0[u] + a0[u] + b0h);
            float z = sigm(gp1[u] + o1[u] + a1[u] + b1h);
            float n = tanhf(gp2v[u] + o2[u] + r*(a2[u] + b2h));
            float hn = (1.0f - z)*n + z*hold[u];
            hbuf[(cur^1)*(NB*NH) + b*NH + jC] = hn;
            pred[((size_t)b*NT + t)*1024 + jC] = hn;
          }
        }
        __syncthreads();   // before next pass overwrites hc
      }
    }
    cur ^= 1;
    grid_bar(bar, 64);
  }
}

// ---------------- launch ----------------
extern "C" void kernel_launch(void* const* d_in, const int* in_sizes, int n_in,
                              void* d_out, int out_size, void* d_ws, size_t ws_size,
                              hipStream_t stream)
{
  const int*   src     = (const int*)  d_in[0];
  const int*   tgt     = (const int*)  d_in[2];
  const float* enc_emb = (const float*)d_in[3];
  const float* enc_Wih = (const float*)d_in[4];
  const float* enc_Whh = (const float*)d_in[5];
  const float* enc_bih = (const float*)d_in[6];
  const float* enc_bhh = (const float*)d_in[7];
  const float* dec_emb = (const float*)d_in[8];
  const float* dec_Wih = (const float*)d_in[9];
  const float* dec_Whh = (const float*)d_in[10];
  const float* dec_bih = (const float*)d_in[11];
  const float* dec_bhh = (const float*)d_in[12];
  const float* fc_W    = (const float*)d_in[13];
  const float* fc_b    = (const float*)d_in[14];
  float* out = (float*)d_out;
  (void)in_sizes; (void)n_in; (void)out_size; (void)ws_size;

  // Big intermediates live in d_out (262MB; all dead before the FC GEMM
  // overwrites it). Only data read DURING the FC GEMM (pred) + tiny state in ws.
  uint8_t* ob = (uint8_t*)d_out;
  size_t oof = 0;
  auto oalloc = [&](size_t bytes) -> void* {
    void* p = ob + oof; oof += (bytes + 255) & ~(size_t)255; return p;
  };
  float* emb_e  = (float*)oalloc((size_t)NB*NS*NE*4);    //  8.4MB
  float* gi_enc = (float*)oalloc((size_t)NB*NS*NG*4);    // 50.3MB
  float* enc_o  = (float*)oalloc((size_t)NB*NS*NH*4);    // 16.8MB
  float* emb_d  = (float*)oalloc((size_t)NB*NT*NE*4);    //  2.1MB
  float* gi_dec = (float*)oalloc((size_t)NB*NT*NG*4);    // 12.6MB

  uint8_t* wb = (uint8_t*)d_ws;
  size_t wof = 0;
  auto walloc = [&](size_t bytes) -> void* {
    void* p = wb + wof; wof += (bytes + 255) & ~(size_t)255; return p;
  };
  float* hbuf   = (float*)walloc((size_t)2*NB*NH*4);         // 128KB
  int*   bar    = (int*)  walloc(2048);
  float* scores = (float*)walloc((size_t)NB*NS*4);           // 32KB
  float* ctxb   = (float*)walloc((size_t)NB*NH*4);           // 64KB
  float* pred   = (float*)walloc((size_t)NB*NT*2*NH*4);      // 8.4MB (read during FC)

  hipLaunchKernelGGL(init_k, dim3(64), dim3(256), 0, stream, hbuf, bar);
  hipLaunchKernelGGL(gather_k, dim3(NB*NS), dim3(64), 0, stream, enc_emb, src, emb_e);
  hipLaunchKernelGGL(gather_k, dim3(NB*NT), dim3(64), 0, stream, dec_emb, tgt, emb_d);
  // gi_enc = emb_e @ enc_Wih^T + bih   [8192 x 1536], K=256
  hipLaunchKernelGGL(gemm_k, dim3(NG/128, (NB*NS)/128), dim3(256), 0, stream,
                     emb_e, NE, enc_Wih, NE, enc_bih, gi_enc, NG, NE, 0);
  // gi_dec = emb_d @ dec_Wih[:, :256]^T + bih   [2048 x 1536], K=256 (ldb=768)
  hipLaunchKernelGGL(gemm_k, dim3(NG/128, (NB*NT)/128), dim3(256), 0, stream,
                     emb_d, NE, dec_Wih, 768, dec_bih, gi_dec, NG, NE, 0);
  hipLaunchKernelGGL(enc_rec_k, dim3(64), dim3(1024), 0, stream,
                     gi_enc, enc_Whh, enc_bhh, hbuf, enc_o, bar);
  hipLaunchKernelGGL(dec_rec_k, dim3(64), dim3(1024), 0, stream,
                     gi_dec, dec_Whh, dec_Wih, dec_bhh, enc_o, src, hbuf, scores, ctxb, pred, bar);
  // logits = pred @ fc_W^T + fc_b   [2048 x 32000], K=1024; mswap=1: m-tiles
  // launch-adjacent -> fc_W panel L2-reused (LLC traffic ~139MB not 2.1GB)
  hipLaunchKernelGGL(gemm_k, dim3((NB*NT)/128, NV/128), dim3(256), 0, stream,
                     pred, 2*NH, fc_W, 2*NH, fc_b, out, NV, 2*NH, 1);
}

// Round 3
// 13595.323 us; speedup vs baseline: 1.9150x; 1.9150x over previous
//
#include <hip/hip_runtime.h>
#include <stdint.h>

#define NV 32000
#define NE 256
#define NH 512
#define NB 32
#define NS 256
#define NT 64
#define NG 1536   // 3*NH

typedef unsigned short u16;
typedef unsigned int   u32;
typedef unsigned long long u64;
typedef short bf16x8 __attribute__((ext_vector_type(8)));
typedef float f32x4  __attribute__((ext_vector_type(4)));

#define AGT __HIP_MEMORY_SCOPE_AGENT
#define RLX __ATOMIC_RELAXED

__device__ __forceinline__ u16 f2bf(float x){
  u32 u = __float_as_uint(x);
  u32 r = (u + 0x7FFFu + ((u >> 16) & 1u)) >> 16;   // RNE
  return (u16)r;
}
__device__ __forceinline__ float bf2f(u16 b){ return __uint_as_float(((u32)b) << 16); }
__device__ __forceinline__ float sigm(float x){ return 1.0f / (1.0f + expf(-x)); }

// coherent (LLC, sc0/sc1) helpers: relaxed agent-scope atomics — no cache-ops
__device__ __forceinline__ float4 co_ld16(const float* p){
  u64 q0 = __hip_atomic_load((const u64*)p,     RLX, AGT);
  u64 q1 = __hip_atomic_load((const u64*)p + 1, RLX, AGT);
  float4 v;
  v.x = __uint_as_float((u32)q0); v.y = __uint_as_float((u32)(q0 >> 32));
  v.z = __uint_as_float((u32)q1); v.w = __uint_as_float((u32)(q1 >> 32));
  return v;
}
__device__ __forceinline__ void co_st4(float* p, float v){
  __hip_atomic_store(p, v, RLX, AGT);
}

// ---------------- grid barrier: flag-array, fence-free ----------------
// Arrive: release-store flags[bid] (one 128B line each). Wait: wave 0 polls all
// 64 flags with RELAXED coherent loads (no L1/L2 invalidates). Data visibility
// comes from write-through atomic stores drained by __syncthreads (vmcnt(0))
// BEFORE the flag store — LLC is the single serialization point.
__device__ __forceinline__ void grid_bar(int* flags, int it, int bid){
  __syncthreads();
  if (threadIdx.x < 64){
    if (threadIdx.x == 0)
      __hip_atomic_store(&flags[bid*32], it, __ATOMIC_RELEASE, AGT);
    for (;;){
      int v = __hip_atomic_load(&flags[threadIdx.x*32], RLX, AGT);
      if (__ballot(v < it) == 0ull) break;
      __builtin_amdgcn_s_sleep(1);
    }
  }
  __syncthreads();
}

// ---------------- init: zero h0 and both flag arrays ----------------
__global__ void init_k(float* __restrict__ hbuf, int* __restrict__ flags){
  int i = blockIdx.x * 256 + threadIdx.x;   // 128 blocks x 256 = 32768
  if (i < 2*NB*NH) hbuf[i] = 0.0f;
  if (i < 4096)    flags[i] = 0;            // enc flags (2048 ints) + dec flags
}

// ---------------- embedding gather (f32 rows) ----------------
__global__ void gather_k(const float* __restrict__ table, const int* __restrict__ idx,
                         float* __restrict__ outp){
  int r = blockIdx.x, c = threadIdx.x;            // 64 threads * 4 f32 = 256 cols
  int row = idx[r];
  float4 v = ((const float4*)(table + (size_t)row * NE))[c];
  ((float4*)(outp + (size_t)r*NE))[c] = v;
}

// ---------------- GEMM: C[M,N] = A * B^T + bias, A f32 split hi/lo in-stage ----
__device__ __forceinline__ void st_hilo8(u16* ph, u16* pl, float4 va, float4 vb){
  float f[8] = {va.x,va.y,va.z,va.w,vb.x,vb.y,vb.z,vb.w};
  u32 hw[4], lw[4];
  #pragma unroll
  for (int i=0;i<4;i++){
    u16 h0 = f2bf(f[2*i]),               h1 = f2bf(f[2*i+1]);
    u16 l0 = f2bf(f[2*i]   - bf2f(h0));
    u16 l1 = f2bf(f[2*i+1] - bf2f(h1));
    hw[i] = (u32)h0 | ((u32)h1 << 16);
    lw[i] = (u32)l0 | ((u32)l1 << 16);
  }
  *(uint4*)ph = *(const uint4*)hw;
  *(uint4*)pl = *(const uint4*)lw;
}
__device__ __forceinline__ void st_b8(u16* p, float4 va, float4 vb){
  u32 w[4];
  w[0] = (u32)f2bf(va.x) | ((u32)f2bf(va.y) << 16);
  w[1] = (u32)f2bf(va.z) | ((u32)f2bf(va.w) << 16);
  w[2] = (u32)f2bf(vb.x) | ((u32)f2bf(vb.y) << 16);
  w[3] = (u32)f2bf(vb.z) | ((u32)f2bf(vb.w) << 16);
  *(uint4*)p = *(const uint4*)w;
}

__global__ __launch_bounds__(256, 2)
void gemm_k(const float* __restrict__ Am, int lda,
            const float* __restrict__ Bm, int ldb, const float* __restrict__ bias,
            float* __restrict__ C, int ldc, int K, int mswap)
{
  __shared__ u16 sAh[128][40];
  __shared__ u16 sAl[128][40];
  __shared__ u16 sB [128][40];
  const int tid = threadIdx.x;
  const int bm = mswap ? blockIdx.x : blockIdx.y;
  const int bn = mswap ? blockIdx.y : blockIdx.x;
  const int m0 = bm * 128, n0 = bn * 128;
  const int w = tid >> 6, lane = tid & 63;
  const int wr = w >> 1, wc = w & 1;
  const int fr = lane & 15, fq = lane >> 4;
  const int fk = fq * 8;

  f32x4 acc[4][4];
  #pragma unroll
  for (int i=0;i<4;i++)
    #pragma unroll
    for (int j=0;j<4;j++)
      #pragma unroll
      for (int e=0;e<4;e++) acc[i][j][e] = 0.0f;

  const int srow = tid >> 1;
  const int sh16 = (tid & 1) * 16;
  const float* gA = Am + (size_t)(m0 + srow)*lda + sh16;
  const float* gB = Bm + (size_t)(n0 + srow)*ldb + sh16;

  float4 ra0 = *(const float4*)(gA),      ra1 = *(const float4*)(gA + 4);
  float4 ra2 = *(const float4*)(gA + 8),  ra3 = *(const float4*)(gA + 12);
  float4 rb0 = *(const float4*)(gB),      rb1 = *(const float4*)(gB + 4);
  float4 rb2 = *(const float4*)(gB + 8),  rb3 = *(const float4*)(gB + 12);

  for (int k0 = 0; k0 < K; k0 += 32){
    st_hilo8(&sAh[srow][sh16],   &sAl[srow][sh16],   ra0, ra1);
    st_hilo8(&sAh[srow][sh16+8], &sAl[srow][sh16+8], ra2, ra3);
    st_b8(&sB[srow][sh16],   rb0, rb1);
    st_b8(&sB[srow][sh16+8], rb2, rb3);

    if (k0 + 32 < K){   // prefetch next K-tile
      ra0 = *(const float4*)(gA + k0+32); ra1 = *(const float4*)(gA + k0+36);
      ra2 = *(const float4*)(gA + k0+40); ra3 = *(const float4*)(gA + k0+44);
      rb0 = *(const float4*)(gB + k0+32); rb1 = *(const float4*)(gB + k0+36);
      rb2 = *(const float4*)(gB + k0+40); rb3 = *(const float4*)(gB + k0+44);
    }
    __syncthreads();
    bf16x8 afh[4], afl[4], bfv[4];
    #pragma unroll
    for (int i=0;i<4;i++){
      afh[i] = *(const bf16x8*)&sAh[wr*64 + i*16 + fr][fk];
      afl[i] = *(const bf16x8*)&sAl[wr*64 + i*16 + fr][fk];
    }
    #pragma unroll
    for (int jj=0;jj<4;jj++) bfv[jj] = *(const bf16x8*)&sB[wc*64 + jj*16 + fr][fk];
    #pragma unroll
    for (int i=0;i<4;i++)
      #pragma unroll
      for (int jj=0;jj<4;jj++){
        acc[i][jj] = __builtin_amdgcn_mfma_f32_16x16x32_bf16(afh[i], bfv[jj], acc[i][jj], 0,0,0);
        acc[i][jj] = __builtin_amdgcn_mfma_f32_16x16x32_bf16(afl[i], bfv[jj], acc[i][jj], 0,0,0);
      }
    __syncthreads();
  }
  #pragma unroll
  for (int jj=0;jj<4;jj++){
    int gn = n0 + wc*64 + jj*16 + fr;
    float bv = bias[gn];
    #pragma unroll
    for (int i=0;i<4;i++){
      int gm = m0 + wr*64 + i*16 + fq*4;
      #pragma unroll
      for (int e=0;e<4;e++)
        C[(size_t)(gm + e)*ldc + gn] = acc[i][jj][e] + bv;
    }
  }
}

// swizzle helper for LDS float4 layout (breaks 128B-stride bank conflicts)
__device__ __forceinline__ int swz(int c){ return c ^ ((c >> 3) & 7); }

// ---------------- encoder recurrence: persistent, 64 blocks x 1024 ----------------
__global__ __launch_bounds__(1024, 1)
void enc_rec_k(const float* __restrict__ gi, const float* __restrict__ Whh,
               const float* __restrict__ bhh, float* __restrict__ hbuf,
               float* __restrict__ enc_out, int* __restrict__ flags)
{
  __shared__ float hl[NB*NH];    // 64KB, float4-swizzled
  const int tid = threadIdx.x, bid = blockIdx.x;
  const int kg = tid & 15;
  const int jl = (tid >> 4) & 7;
  const int bq = tid >> 7;
  const int j  = bid * 8 + jl;
  float w0[32], w1[32], w2[32];
  {
    const float* p0 = Whh + (size_t)(0*NH + j)*NH + kg*32;
    const float* p1 = Whh + (size_t)(1*NH + j)*NH + kg*32;
    const float* p2 = Whh + (size_t)(2*NH + j)*NH + kg*32;
    #pragma unroll
    for (int q=0;q<8;q++){
      *(float4*)&w0[q*4] = *(const float4*)(p0 + q*4);
      *(float4*)&w1[q*4] = *(const float4*)(p1 + q*4);
      *(float4*)&w2[q*4] = *(const float4*)(p2 + q*4);
    }
  }
  const float b0 = bhh[j], b1 = bhh[NH+j], b2 = bhh[2*NH+j];
  int cur = 0;
  for (int s=0; s<NS; s++){
    const float* hsrc = hbuf + cur*(NB*NH);
    float g0[4], g1[4], g2[4];
    if (kg == 0){                      // prefetch gate inputs early (plain: gi is stable)
      #pragma unroll
      for (int u=0;u<4;u++){
        int b = bq*4 + u;
        const float* gp = gi + ((size_t)b*NS + s)*NG;
        g0[u] = gp[j]; g1[u] = gp[NH+j]; g2[u] = gp[2*NH+j];
      }
    }
    #pragma unroll
    for (int u=0;u<4;u++){             // stage h into swizzled LDS (coherent loads)
      int i4 = tid + u*1024;
      int b = i4 >> 7, c = i4 & 127;
      ((float4*)hl)[b*128 + swz(c)] = co_ld16(hsrc + (size_t)b*NH + c*4);
    }
    __syncthreads();
    float a0[4], a1[4], a2[4];
    #pragma unroll
    for (int u=0;u<4;u++){
      int b = bq*4 + u;
      float hv[32];
      #pragma unroll
      for (int q=0;q<8;q++)
        *(float4*)&hv[q*4] = ((float4*)hl)[b*128 + kg*8 + (q ^ (kg & 7))];
      float s0=0.f, s1=0.f, s2=0.f;
      #pragma unroll
      for (int kk=0;kk<32;kk++){ s0+=w0[kk]*hv[kk]; s1+=w1[kk]*hv[kk]; s2+=w2[kk]*hv[kk]; }
      a0[u]=s0; a1[u]=s1; a2[u]=s2;
    }
    #pragma unroll
    for (int m=1;m<16;m<<=1){
      #pragma unroll
      for (int u=0;u<4;u++){
        a0[u] += __shfl_xor(a0[u], m);
        a1[u] += __shfl_xor(a1[u], m);
        a2[u] += __shfl_xor(a2[u], m);
      }
    }
    if (kg == 0){
      #pragma unroll
      for (int u=0;u<4;u++){
        int b = bq*4 + u;
        float hold = hl[(b*128 + swz(j>>2))*4 + (j&3)];   // from staged LDS copy
        float r = sigm(g0[u] + a0[u] + b0);
        float z = sigm(g1[u] + a1[u] + b1);
        float n = tanhf(g2[u] + r*(a2[u] + b2));
        float hn = (1.0f - z)*n + z*hold;
        co_st4(&hbuf[(cur^1)*(NB*NH) + b*NH + j], hn);    // write-through to LLC
        enc_out[((size_t)b*NS + s)*NH + j] = hn;          // plain (next-kernel consumer)
      }
    }
    cur ^= 1;
    grid_bar(flags, s+1, bid);
  }
}

// ---------------- decoder recurrence: persistent, 64 blocks x 1024, 2 phases/step ----
__global__ __launch_bounds__(1024, 1)
void dec_rec_k(const float* __restrict__ gi, const float* __restrict__ Whh,
               const float* __restrict__ Wih, const float* __restrict__ bhh,
               const float* __restrict__ enc_out, const int* __restrict__ src,
               float* __restrict__ hbuf, float* __restrict__ ctx,
               float* __restrict__ pred, int* __restrict__ flags)
{
  __shared__ float pool[16384];   // 64KB
  const int tid = threadIdx.x, bid = blockIdx.x;
  // phase C mapping: kg: 32 k-slices of 32 over k=1024 (h||ctx); rl: 8 j's; bq: 4
  const int kg = tid & 31;
  const int rl = (tid >> 5) & 7;
  const int bq = tid >> 8;
  const int jC = bid * 8 + rl;
  float w0[32], w1[32], w2[32];
  {
    const float* p0 = (kg < 16) ? (Whh + (size_t)(0*NH+jC)*NH + kg*32)
                                : (Wih + (size_t)(0*NH+jC)*768 + NE + (kg-16)*32);
    const float* p1 = (kg < 16) ? (Whh + (size_t)(1*NH+jC)*NH + kg*32)
                                : (Wih + (size_t)(1*NH+jC)*768 + NE + (kg-16)*32);
    const float* p2 = (kg < 16) ? (Whh + (size_t)(2*NH+jC)*NH + kg*32)
                                : (Wih + (size_t)(2*NH+jC)*768 + NE + (kg-16)*32);
    #pragma unroll
    for (int q=0;q<8;q++){
      *(float4*)&w0[q*4] = *(const float4*)(p0 + q*4);
      *(float4*)&w1[q*4] = *(const float4*)(p1 + q*4);
      *(float4*)&w2[q*4] = *(const float4*)(p2 + q*4);
    }
  }
  const float b0h = bhh[jC], b1h = bhh[NH+jC], b2h = bhh[2*NH+jC];

  int cur = 0;
  for (int t=0; t<NT; t++){
    // ---- AB: per-batch scores + softmax + context (block b = bid < 32) ----
    if (bid < NB){
      const int b = bid;
      float* hb   = pool;          // 512
      float* sc   = pool + 512;    // 256 (scores then attn)
      float* red  = pool + 768;    // 16
      float* part = pool + 1024;   // [8][512]
      const float* hsrc = hbuf + cur*(NB*NH) + (size_t)b*NH;
      if (tid < 256){
        u64 wq = __hip_atomic_load((const u64*)hsrc + tid, RLX, AGT);
        hb[2*tid]   = __uint_as_float((u32)wq);
        hb[2*tid+1] = __uint_as_float((u32)(wq >> 32));
      }
      __syncthreads();
      { // scores: s = tid>>2, q = tid&3 covers k in [q*128, q*128+128)
        int s = tid >> 2, q = tid & 3;
        const float* eo = enc_out + ((size_t)b*NS + s)*NH + q*128;
        const float* hq = hb + q*128;
        float d = 0.f;
        #pragma unroll
        for (int kk=0; kk<128; kk+=4){
          float4 e  = *(const float4*)(eo + kk);
          float4 hv = *(const float4*)(hq + kk);
          d += e.x*hv.x + e.y*hv.y + e.z*hv.z + e.w*hv.w;
        }
        d += __shfl_xor(d,1); d += __shfl_xor(d,2);
        if (q == 0){
          int tok = src[b*NS + s];
          sc[s] = (tok == 0) ? -1e9f : d;
        }
      }
      __syncthreads();
      { // softmax over sc[256]
        float sv = (tid < 256) ? sc[tid] : -1e30f;
        float mx = sv;
        #pragma unroll
        for (int m=1;m<64;m<<=1) mx = fmaxf(mx, __shfl_xor(mx, m));
        if (tid < 256 && (tid & 63) == 0) red[tid>>6] = mx;
        __syncthreads();
        mx = fmaxf(fmaxf(red[0], red[1]), fmaxf(red[2], red[3]));
        float ex = (tid < 256) ? expf(sv - mx) : 0.0f;
        float sm = ex;
        #pragma unroll
        for (int m=1;m<64;m<<=1) sm += __shfl_xor(sm, m);
        if (tid < 256 && (tid & 63) == 0) red[8 + (tid>>6)] = sm;
        __syncthreads();
        float tot = red[8] + red[9] + red[10] + red[11];
        if (tid < 256) sc[tid] = ex / tot;
      }
      __syncthreads();
      { // context: h4 = float4 col (128), sg = 8 groups of 32 s
        int h4 = tid & 127, sg = tid >> 7;
        const float* eob = enc_out + (size_t)b*NS*NH + h4*4;
        float4 a; a.x=a.y=a.z=a.w=0.f;
        for (int s5=0; s5<32; s5++){
          int s = sg*32 + s5;
          float wv = sc[s];
          float4 e = *(const float4*)(eob + (size_t)s*NH);
          a.x += wv*e.x; a.y += wv*e.y; a.z += wv*e.z; a.w += wv*e.w;
        }
        *(float4*)&part[sg*512 + h4*4] = a;
      }
      __syncthreads();
      if (tid < 512){
        float c = 0.f;
        #pragma unroll
        for (int g=0;g<8;g++) c += part[g*512 + tid];
        co_st4(&ctx[(size_t)b*NH + tid], c);                      // LLC write-through
        pred[((size_t)b*NT + t)*1024 + NH + tid] = c;             // plain
      }
    }
    grid_bar(flags, 2*t+1, bid);
    // ---- C: gates; j-partitioned; 2 passes of 16 b (64KB LDS) ----
    {
      const float* hsrc = hbuf + cur*(NB*NH);
      #pragma unroll 1
      for (int p2=0; p2<2; ++p2){
        float* hc = pool;   // [16][256 float4] swizzled: h || ctx per row
        float gp0[4], gp1[4], gp2v[4];
        if (kg == 0){
          #pragma unroll
          for (int u=0;u<4;u++){
            int b = p2*16 + bq*4 + u;
            const float* gp = gi + ((size_t)b*NT + t)*NG;
            gp0[u] = gp[jC]; gp1[u] = gp[NH+jC]; gp2v[u] = gp[2*NH+jC];
          }
        }
        #pragma unroll
        for (int u=0;u<4;u++){
          int i4 = tid + u*1024;         // 4096 f4 = 16 b x 256
          int bl = i4 >> 8, c = i4 & 255;
          const float* sp = (c < 128) ? (hsrc + (size_t)(p2*16+bl)*NH + c*4)
                                      : (ctx  + (size_t)(p2*16+bl)*NH + (c-128)*4);
          ((float4*)hc)[bl*256 + swz(c)] = co_ld16(sp);
        }
        __syncthreads();
        float a0[4], a1[4], a2[4];
        #pragma unroll
        for (int u=0;u<4;u++){
          int bl = bq*4 + u;
          float hv[32];
          #pragma unroll
          for (int q=0;q<8;q++)
            *(float4*)&hv[q*4] = ((float4*)hc)[bl*256 + kg*8 + (q ^ (kg & 7))];
          float s0=0.f,s1=0.f,s2=0.f;
          #pragma unroll
          for (int kk=0;kk<32;kk++){ s0+=w0[kk]*hv[kk]; s1+=w1[kk]*hv[kk]; s2+=w2[kk]*hv[kk]; }
          a0[u]=s0; a1[u]=s1; a2[u]=s2;
        }
        #pragma unroll
        for (int m=1;m<16;m<<=1){
          #pragma unroll
          for (int u=0;u<4;u++){
            a0[u]+=__shfl_xor(a0[u],m); a1[u]+=__shfl_xor(a1[u],m); a2[u]+=__shfl_xor(a2[u],m);
          }
        }
        float o0[4], o1[4], o2[4];   // other half (gh at kg0 <-> gi-ctx at kg16)
        #pragma unroll
        for (int u=0;u<4;u++){
          o0[u]=__shfl_xor(a0[u],16); o1[u]=__shfl_xor(a1[u],16); o2[u]=__shfl_xor(a2[u],16);
        }
        if (kg == 0){
          #pragma unroll
          for (int u=0;u<4;u++){
            int b = p2*16 + bq*4 + u;
            int bl = bq*4 + u;
            float hold = hc[(bl*256 + swz(jC>>2))*4 + (jC&3)];
            float r = sigm(gp0[u] + o0[u] + a0[u] + b0h);
            float z = sigm(gp1[u] + o1[u] + a1[u] + b1h);
            float n = tanhf(gp2v[u] + o2[u] + r*(a2[u] + b2h));
            float hn = (1.0f - z)*n + z*hold;
            co_st4(&hbuf[(cur^1)*(NB*NH) + b*NH + jC], hn);
            pred[((size_t)b*NT + t)*1024 + jC] = hn;
          }
        }
        __syncthreads();   // before next pass overwrites hc
      }
    }
    cur ^= 1;
    grid_bar(flags, 2*t+2, bid);
  }
}

// ---------------- launch ----------------
extern "C" void kernel_launch(void* const* d_in, const int* in_sizes, int n_in,
                              void* d_out, int out_size, void* d_ws, size_t ws_size,
                              hipStream_t stream)
{
  const int*   src     = (const int*)  d_in[0];
  const int*   tgt     = (const int*)  d_in[2];
  const float* enc_emb = (const float*)d_in[3];
  const float* enc_Wih = (const float*)d_in[4];
  const float* enc_Whh = (const float*)d_in[5];
  const float* enc_bih = (const float*)d_in[6];
  const float* enc_bhh = (const float*)d_in[7];
  const float* dec_emb = (const float*)d_in[8];
  const float* dec_Wih = (const float*)d_in[9];
  const float* dec_Whh = (const float*)d_in[10];
  const float* dec_bih = (const float*)d_in[11];
  const float* dec_bhh = (const float*)d_in[12];
  const float* fc_W    = (const float*)d_in[13];
  const float* fc_b    = (const float*)d_in[14];
  float* out = (float*)d_out;
  (void)in_sizes; (void)n_in; (void)out_size; (void)ws_size;

  // Big intermediates live in d_out (262MB; all dead before the FC GEMM
  // overwrites it). Only data read DURING the FC GEMM (pred) + state in ws.
  uint8_t* ob = (uint8_t*)d_out;
  size_t oof = 0;
  auto oalloc = [&](size_t bytes) -> void* {
    void* p = ob + oof; oof += (bytes + 255) & ~(size_t)255; return p;
  };
  float* emb_e  = (float*)oalloc((size_t)NB*NS*NE*4);    //  8.4MB
  float* gi_enc = (float*)oalloc((size_t)NB*NS*NG*4);    // 50.3MB
  float* enc_o  = (float*)oalloc((size_t)NB*NS*NH*4);    // 16.8MB
  float* emb_d  = (float*)oalloc((size_t)NB*NT*NE*4);    //  2.1MB
  float* gi_dec = (float*)oalloc((size_t)NB*NT*NG*4);    // 12.6MB

  uint8_t* wb = (uint8_t*)d_ws;
  size_t wof = 0;
  auto walloc = [&](size_t bytes) -> void* {
    void* p = wb + wof; wof += (bytes + 255) & ~(size_t)255; return p;
  };
  float* hbuf   = (float*)walloc((size_t)2*NB*NH*4);         // 128KB
  int*   flags  = (int*)  walloc(16384);                     // enc[2048] + dec[2048] ints
  float* ctxb   = (float*)walloc((size_t)NB*NH*4);           // 64KB
  float* pred   = (float*)walloc((size_t)NB*NT*2*NH*4);      // 8.4MB (read during FC)
  int*   flags_d = flags + 2048;

  hipLaunchKernelGGL(init_k, dim3(128), dim3(256), 0, stream, hbuf, flags);
  hipLaunchKernelGGL(gather_k, dim3(NB*NS), dim3(64), 0, stream, enc_emb, src, emb_e);
  hipLaunchKernelGGL(gather_k, dim3(NB*NT), dim3(64), 0, stream, dec_emb, tgt, emb_d);
  // gi_enc = emb_e @ enc_Wih^T + bih   [8192 x 1536], K=256
  hipLaunchKernelGGL(gemm_k, dim3(NG/128, (NB*NS)/128), dim3(256), 0, stream,
                     emb_e, NE, enc_Wih, NE, enc_bih, gi_enc, NG, NE, 0);
  // gi_dec = emb_d @ dec_Wih[:, :256]^T + bih   [2048 x 1536], K=256 (ldb=768)
  hipLaunchKernelGGL(gemm_k, dim3(NG/128, (NB*NT)/128), dim3(256), 0, stream,
                     emb_d, NE, dec_Wih, 768, dec_bih, gi_dec, NG, NE, 0);
  hipLaunchKernelGGL(enc_rec_k, dim3(64), dim3(1024), 0, stream,
                     gi_enc, enc_Whh, enc_bhh, hbuf, enc_o, flags);
  hipLaunchKernelGGL(dec_rec_k, dim3(64), dim3(1024), 0, stream,
                     gi_dec, dec_Whh, dec_Wih, dec_bhh, enc_o, src, hbuf, ctxb, pred, flags_d);
  // logits = pred @ fc_W^T + fc_b   [2048 x 32000], K=1024; mswap=1: m-tiles
  // launch-adjacent -> fc_W panel L2-reused
  hipLaunchKernelGGL(gemm_k, dim3((NB*NT)/128, NV/128), dim3(256), 0, stream,
                     pred, 2*NH, fc_W, 2*NH, fc_b, out, NV, 2*NH, 1);
}